// Round 10
// baseline (376.471 us; speedup 1.0000x reference)
//
#include <hip/hip_runtime.h>
#include <hip/hip_bf16.h>
#include <stdint.h>

#define NN 50000
#define NE 800000
#define CC 96
#define NL 3
#define NMT 3125          // M-tiles (16 nodes each)
#define SLAB (NN*32)      // fp16 elems per channel-slab (3 slabs of 32 ch)

// fp16 fragment-packed weights: per layer: 6 tcol x 6 sets (0-2 Wc gates, 3-5 Whh gates)
// x 3 ks x 64 lanes x 8 fp16 = 55296 elems = 108 KB
#define ELEMS_PER_LAYER 55296

typedef _Float16 f16x8 __attribute__((ext_vector_type(8)));
typedef float f32x4 __attribute__((ext_vector_type(4)));
typedef uint16_t u16x8 __attribute__((ext_vector_type(8)));

__device__ __forceinline__ uint16_t f2h(float f){
  _Float16 h = (_Float16)f;
  return __builtin_bit_cast(uint16_t, h);
}
__device__ __forceinline__ float h2f(uint16_t u){
  return (float)__builtin_bit_cast(_Float16, u);
}

__global__ void k_hist(const int* __restrict__ dstv, int* __restrict__ counts){
  int e = blockIdx.x*256 + threadIdx.x;
  if(e < NE) atomicAdd(&counts[dstv[e]], 1);
}

// Scan-free bucket assignment (CSR bucket order is arbitrary): wave-prefix-scan
// + one global-cursor atomic per wave.
__global__ void k_assign(const int* __restrict__ counts, int* __restrict__ offsets,
                         int* __restrict__ cursor, int* __restrict__ gcur){
  int i = blockIdx.x*256 + threadIdx.x;
  int lane = threadIdx.x & 63;
  int v = (i < NN) ? counts[i] : 0;
  int sum = v;
  #pragma unroll
  for(int d=1; d<64; d<<=1){
    int t = __shfl_up(sum, d, 64);
    if(lane >= d) sum += t;
  }
  int total = __shfl(sum, 63, 64);
  int base = 0;
  if(lane == 63) base = atomicAdd(gcur, total);
  base = __shfl(base, 63, 64);
  int off = base + sum - v;
  if(i < NN){ offsets[i] = off; cursor[i] = off; }
}

__global__ void k_fill(const int* __restrict__ srcv, const int* __restrict__ dstv,
                       int* __restrict__ cursor, int* __restrict__ ssrc){
  int e = blockIdx.x*256 + threadIdx.x;
  if(e < NE){
    int d = dstv[e];
    int pos = atomicAdd(&cursor[d], 1);
    ssrc[pos] = srcv[e];
  }
}

// Merged prep: f32->fp16 x table in 3-slab layout (idx < N8) + fragment-packed
// fp16 weights. fe(tcol,g2,ks,lane,j); g2: 0-2 Wc r/z/n, 3-5 Whh r/z/n.
// B-frag (16x16x32): element (k = ks*32 + (lane>>4)*8 + j, n = lane&15).
__device__ __forceinline__ size_t frag_elem(int tcol, int g2, int ks, int lane, int j){
  return (((size_t)(tcol*6 + g2)*3 + ks)*64 + lane)*8 + j;
}
__global__ void k_prep(const float4* __restrict__ x, u16x8* __restrict__ xh,
                       const float* __restrict__ weight, const float* __restrict__ w_ih,
                       const float* __restrict__ w_hh, uint16_t* __restrict__ gw){
  int idx = blockIdx.x*256 + threadIdx.x;
  const int N8 = NN*CC/8;          // 600000
  if(idx < N8){
    int n = idx / 12, c8 = idx - n*12;
    float4 a = x[(size_t)n*24 + 2*c8], b = x[(size_t)n*24 + 2*c8 + 1];
    u16x8 o;
    o[0]=f2h(a.x); o[1]=f2h(a.y); o[2]=f2h(a.z); o[3]=f2h(a.w);
    o[4]=f2h(b.x); o[5]=f2h(b.y); o[6]=f2h(b.z); o[7]=f2h(b.w);
    // slab (c8>>2), within-slab chunk n*4 + (c8&3)
    xh[(size_t)(c8>>2)*(SLAB/8) + (size_t)n*4 + (c8&3)] = o;
    return;
  }
  int pidx = idx - N8;
  const int TOT1 = NL*288*CC;      // Wc: (l, col, k)
  const int TOT2 = 288*CC;         // Whh: (col, k), replicated to all layers
  if(pidx < TOT1){
    int k = pidx % CC;
    int col = (pidx / CC) % 288;
    int l = pidx / (CC*288);
    // Wc[k][col] = sum_k2 weight[l][k][k2] * w_ih[col][k2]
    const float4* wr = (const float4*)(weight + (size_t)(l*CC + k)*CC);
    const float4* ir = (const float4*)(w_ih + (size_t)col*CC);
    float acc = 0.f;
    #pragma unroll 4
    for(int k2=0;k2<CC/4;k2++){
      float4 a = wr[k2], b = ir[k2];
      acc += a.x*b.x + a.y*b.y + a.z*b.z + a.w*b.w;
    }
    int g = col / 96, cg = col % 96;
    int tcol = cg >> 4, n = cg & 15;
    int ks = k >> 5, r = (k & 31) >> 3, j = k & 7;
    int lane = r*16 + n;
    gw[(size_t)l*ELEMS_PER_LAYER + frag_elem(tcol, g, ks, lane, j)] = f2h(acc);
  } else {
    int idx2 = pidx - TOT1;
    if(idx2 < TOT2){
      int k = idx2 % CC;
      int col = idx2 / CC;
      uint16_t h = f2h(w_hh[(size_t)col*CC + k]);   // gh = x @ w_hh^T: B[k][col] = w_hh[col][k]
      int g = col / 96, cg = col % 96;
      int tcol = cg >> 4, n = cg & 15;
      int ks = k >> 5, r = (k & 31) >> 3, j = k & 7;
      int lane = r*16 + n;
      size_t fe = frag_elem(tcol, 3+g, ks, lane, j);
      #pragma unroll
      for(int l=0;l<NL;l++) gw[(size_t)l*ELEMS_PER_LAYER + fe] = h;
    }
  }
}

// CSR aggregation, ONE CHANNEL-SLAB per dispatch: xh_p/s_p point at a 3.2 MB
// slab that fits an XCD's 4 MB L2 -> edge gathers are L2 hits, each edge
// row-part is exactly one 64 B line. thread = (node, c) with c in [0,4).
__global__ void k_aggregate(const u16x8* __restrict__ xh_p, const int* __restrict__ offsets,
                            const int* __restrict__ counts, const int* __restrict__ ssrc,
                            u16x8* __restrict__ s_p){
  int tid = blockIdx.x*256 + threadIdx.x;
  if(tid >= NN*4) return;
  int n = tid >> 2;
  int c = tid & 3;
  int o0 = offsets[n];
  int o1 = o0 + counts[n];
  float a[8];
  #pragma unroll
  for(int t=0;t<8;t++) a[t] = 0.f;
  int j = o0;
  for(; j+8 <= o1; j+=8){
    int s0 = ssrc[j],   s1 = ssrc[j+1], s2 = ssrc[j+2], s3 = ssrc[j+3];
    int s4 = ssrc[j+4], s5 = ssrc[j+5], s6 = ssrc[j+6], s7 = ssrc[j+7];
    u16x8 v0 = xh_p[(size_t)s0*4 + c];
    u16x8 v1 = xh_p[(size_t)s1*4 + c];
    u16x8 v2 = xh_p[(size_t)s2*4 + c];
    u16x8 v3 = xh_p[(size_t)s3*4 + c];
    u16x8 v4 = xh_p[(size_t)s4*4 + c];
    u16x8 v5 = xh_p[(size_t)s5*4 + c];
    u16x8 v6 = xh_p[(size_t)s6*4 + c];
    u16x8 v7 = xh_p[(size_t)s7*4 + c];
    #pragma unroll
    for(int t=0;t<8;t++)
      a[t] += ((h2f(v0[t])+h2f(v1[t]))+(h2f(v2[t])+h2f(v3[t])))
            + ((h2f(v4[t])+h2f(v5[t]))+(h2f(v6[t])+h2f(v7[t])));
  }
  for(; j < o1; j++){
    u16x8 v = xh_p[(size_t)ssrc[j]*4 + c];
    #pragma unroll
    for(int t=0;t<8;t++) a[t] += h2f(v[t]);
  }
  u16x8 o;
  #pragma unroll
  for(int t=0;t<8;t++) o[t] = f2h(a[t]);
  s_p[tid] = o;
}

#define MFMA16(A,B,C) __builtin_amdgcn_mfma_f32_16x16x32_f16(A,B,C,0,0,0)

// Fused dual-GEMM + GRU (R8 shape: 1024 threads = 16 waves/CU, 1 mtile/wave,
// single barrier). A-fragments map exactly onto the channel slabs (slab = ks).
__global__ __launch_bounds__(1024) void k_gru(
    const uint16_t* __restrict__ s16, const uint16_t* __restrict__ x16,
    const uint16_t* __restrict__ gw_l,
    const float* __restrict__ b_ih, const float* __restrict__ b_hh,
    float* __restrict__ out_f, uint16_t* __restrict__ out_h16)
{
  __shared__ __align__(16) uint16_t lw[ELEMS_PER_LAYER];   // 110592 B

  const int tid = threadIdx.x;
  // stage all 108 KB: 6912 uint4 chunks over 1024 threads
  {
    const uint4* src = (const uint4*)gw_l;
    uint4* dst = (uint4*)lw;
    #pragma unroll
    for(int i=0;i<7;i++){
      int chunk = i*1024 + tid;
      if(chunk < ELEMS_PER_LAYER/8) dst[chunk] = src[chunk];
    }
  }
  __syncthreads();                        // the only barrier

  int wave = tid >> 6;
  int lane = tid & 63;
  int mtile = wave*256 + blockIdx.x;      // cyclic: all 256 blocks/CUs busy
  if(mtile >= NMT) return;                // no more barriers -> early return ok
  int nidx = lane & 15;
  int quad = lane >> 4;

  // A fragments: slab ks holds channels [ks*32, ks*32+32) -> contiguous 16 B
  f16x8 as[3], ax[3];
  {
    size_t r0 = (size_t)(mtile*16 + nidx)*32 + quad*8;
    #pragma unroll
    for(int ks=0; ks<3; ks++){
      as[ks] = *reinterpret_cast<const f16x8*>(s16 + (size_t)ks*SLAB + r0);
      ax[ks] = *reinterpret_cast<const f16x8*>(x16 + (size_t)ks*SLAB + r0);
    }
  }

  #pragma unroll 1
  for(int tcol=0; tcol<6; tcol++){
    f32x4 air = {0.f,0.f,0.f,0.f}, aiz = {0.f,0.f,0.f,0.f}, ain = {0.f,0.f,0.f,0.f};
    f32x4 ahr = {0.f,0.f,0.f,0.f}, ahz = {0.f,0.f,0.f,0.f}, ahn = {0.f,0.f,0.f,0.f};

    #pragma unroll
    for(int ks=0; ks<3; ks++){
      const uint16_t* base = lw + (((size_t)tcol*6)*3 + ks)*512 + lane*8;
      #define BFRAG(g2) (*reinterpret_cast<const f16x8*>(base + (size_t)(g2)*3*512))
      air = MFMA16(as[ks], BFRAG(0), air);
      aiz = MFMA16(as[ks], BFRAG(1), aiz);
      ain = MFMA16(as[ks], BFRAG(2), ain);
      ahr = MFMA16(ax[ks], BFRAG(3), ahr);
      ahz = MFMA16(ax[ks], BFRAG(4), ahz);
      ahn = MFMA16(ax[ks], BFRAG(5), ahn);
      #undef BFRAG
    }

    int c = tcol*16 + nidx;
    int slab = c >> 5, cs = c & 31;
    float bir_ = b_ih[c], biz_ = b_ih[CC+c], bin_ = b_ih[2*CC+c];
    float bhr_ = b_hh[c], bhz_ = b_hh[CC+c], bhn_ = b_hh[2*CC+c];

    #pragma unroll
    for(int r=0;r<4;r++){
      int node = mtile*16 + quad*4 + r;   // C/D: row = quad*4 + reg, col = lane&15
      float ir  = air[r] + bir_;
      float iz  = aiz[r] + biz_;
      float in_ = ain[r] + bin_;
      float hr  = ahr[r] + bhr_;
      float hz  = ahz[r] + bhz_;
      float hn  = ahn[r] + bhn_;
      float rg = 1.f/(1.f + __expf(-(ir+hr)));
      float zg = 1.f/(1.f + __expf(-(iz+hz)));
      float nv = in_ + rg*hn;
      float av = fminf(fabsf(nv), 15.f);
      float e2 = __expf(2.f*av);
      float tg = 1.f - 2.f/(e2 + 1.f);
      tg = (nv < 0.f)? -tg : tg;
      size_t oi = (size_t)slab*SLAB + (size_t)node*32 + cs;
      float hp = h2f(x16[oi]);            // h state lives in the fp16 slab table
      float h = (1.f - zg)*tg + zg*hp;
      if(out_f)   out_f[(size_t)node*CC + c] = h;   // final layer (d_out, f32 row-major)
      if(out_h16) out_h16[oi] = f2h(h);             // intermediate (fp16 slabs)
    }
  }
}

extern "C" void kernel_launch(void* const* d_in, const int* in_sizes, int n_in,
                              void* d_out, int out_size, void* d_ws, size_t ws_size,
                              hipStream_t stream){
  const float* x0     = (const float*)d_in[0];
  const int*   ei     = (const int*)d_in[1];
  const float* weight = (const float*)d_in[2];
  const float* w_ih   = (const float*)d_in[3];
  const float* w_hh   = (const float*)d_in[4];
  const float* b_ih   = (const float*)d_in[5];
  const float* b_hh   = (const float*)d_in[6];
  float* out = (float*)d_out;

  const int* srcv = ei;        // edge_index[0]
  const int* dstv = ei + NE;   // edge_index[1]

  char* ws = (char*)d_ws;
  size_t off = 0;
  auto carve = [&](size_t bytes)->char*{
    char* p = ws + off;
    off += (bytes + 255) & ~(size_t)255;
    return p;
  };
  int* counts   = (int*)carve((size_t)NN*4);
  int* offsets  = (int*)carve((size_t)NN*4);
  int* cursor   = (int*)carve((size_t)NN*4);
  int* gcur     = (int*)carve(4);
  int* ssrc     = (int*)carve((size_t)NE*4);
  uint16_t* s16 = (uint16_t*)carve((size_t)NN*CC*2);    // fp16 aggregate (3 slabs)
  uint16_t* xh16A = (uint16_t*)carve((size_t)NN*CC*2);  // fp16 h slabs ping
  uint16_t* xh16B = (uint16_t*)carve((size_t)NN*CC*2);  // fp16 h slabs pong
  uint16_t* gw  = (uint16_t*)carve((size_t)NL*ELEMS_PER_LAYER*2);

  // CSR build (once — edge structure shared by all 3 layers)
  hipMemsetAsync(counts, 0, (size_t)NN*4, stream);
  hipMemsetAsync(gcur, 0, 4, stream);
  k_hist<<<(NE+255)/256, 256, 0, stream>>>(dstv, counts);
  k_assign<<<(NN+255)/256, 256, 0, stream>>>(counts, offsets, cursor, gcur);
  k_fill<<<(NE+255)/256, 256, 0, stream>>>(srcv, dstv, cursor, ssrc);

  // fp16 slab x table + folded/fragment-packed weights, one dispatch
  k_prep<<<((NN*CC/8 + NL*288*CC + 288*CC)+255)/256, 256, 0, stream>>>(
      (const float4*)x0, (u16x8*)xh16A, weight, w_ih, w_hh, gw);

  uint16_t* xh_cur = xh16A;
  uint16_t* xh_nxt = xh16B;
  for(int l=0; l<NL; l++){
    // aggregation: one dispatch per channel-slab (keeps each 3.2 MB slab L2-hot)
    for(int p=0; p<3; p++){
      k_aggregate<<<((NN*4)+255)/256, 256, 0, stream>>>(
          (const u16x8*)(xh_cur + (size_t)p*SLAB), offsets, counts, ssrc,
          (u16x8*)(s16 + (size_t)p*SLAB));
    }
    float* out_f = (l==NL-1) ? out : nullptr;           // f32 only for final output
    uint16_t* oh = (l==NL-1) ? nullptr : xh_nxt;        // fp16 h for next layer
    k_gru<<<256, 1024, 0, stream>>>(s16, xh_cur,
                                    gw + (size_t)l*ELEMS_PER_LAYER,
                                    b_ih, b_hh, out_f, oh);
    xh_cur = xh_nxt; xh_nxt = (xh_cur == xh16A) ? xh16B : xh16A;
  }
}

// Round 11
// 343.683 us; speedup vs baseline: 1.0954x; 1.0954x over previous
//
#include <hip/hip_runtime.h>
#include <hip/hip_bf16.h>
#include <stdint.h>

#define NN 50000
#define NE 800000
#define CC 96
#define NL 3
#define NMT 3125          // M-tiles (16 nodes each)

// fp16 fragment-packed weights: per layer: 6 tcol x 6 sets (0-2 Wc gates, 3-5 Whh gates)
// x 3 ks x 64 lanes x 8 fp16 = 55296 elems = 108 KB
#define ELEMS_PER_LAYER 55296

typedef _Float16 f16x8 __attribute__((ext_vector_type(8)));
typedef float f32x4 __attribute__((ext_vector_type(4)));
typedef uint16_t u16x8 __attribute__((ext_vector_type(8)));

__device__ __forceinline__ uint16_t f2h(float f){
  _Float16 h = (_Float16)f;
  return __builtin_bit_cast(uint16_t, h);
}
__device__ __forceinline__ float h2f(uint16_t u){
  return (float)__builtin_bit_cast(_Float16, u);
}

__global__ void k_hist(const int* __restrict__ dstv, int* __restrict__ counts){
  int e = blockIdx.x*256 + threadIdx.x;
  if(e < NE) atomicAdd(&counts[dstv[e]], 1);
}

// Scan-free bucket assignment (CSR bucket order is arbitrary): wave-prefix-scan
// + one global-cursor atomic per wave.
__global__ void k_assign(const int* __restrict__ counts, int* __restrict__ offsets,
                         int* __restrict__ cursor, int* __restrict__ gcur){
  int i = blockIdx.x*256 + threadIdx.x;
  int lane = threadIdx.x & 63;
  int v = (i < NN) ? counts[i] : 0;
  int sum = v;
  #pragma unroll
  for(int d=1; d<64; d<<=1){
    int t = __shfl_up(sum, d, 64);
    if(lane >= d) sum += t;
  }
  int total = __shfl(sum, 63, 64);
  int base = 0;
  if(lane == 63) base = atomicAdd(gcur, total);
  base = __shfl(base, 63, 64);
  int off = base + sum - v;
  if(i < NN){ offsets[i] = off; cursor[i] = off; }
}

// CSR fill; ssrc stored as uint16 (node ids < 65536) — halves scatter traffic.
__global__ void k_fill(const int* __restrict__ srcv, const int* __restrict__ dstv,
                       int* __restrict__ cursor, uint16_t* __restrict__ ssrc){
  int e = blockIdx.x*256 + threadIdx.x;
  if(e < NE){
    int d = dstv[e];
    int pos = atomicAdd(&cursor[d], 1);
    ssrc[pos] = (uint16_t)srcv[e];
  }
}

// Merged prep: f32->fp16 x table row-major (idx < N8) + fragment-packed fp16
// weights. fe(tcol,g2,ks,lane,j); g2: 0-2 Wc r/z/n, 3-5 Whh r/z/n.
// B-frag (16x16x32): element (k = ks*32 + (lane>>4)*8 + j, n = lane&15).
__device__ __forceinline__ size_t frag_elem(int tcol, int g2, int ks, int lane, int j){
  return (((size_t)(tcol*6 + g2)*3 + ks)*64 + lane)*8 + j;
}
__global__ void k_prep(const float4* __restrict__ x, u16x8* __restrict__ xh,
                       const float* __restrict__ weight, const float* __restrict__ w_ih,
                       const float* __restrict__ w_hh, uint16_t* __restrict__ gw){
  int idx = blockIdx.x*256 + threadIdx.x;
  const int N8 = NN*CC/8;          // 600000
  if(idx < N8){
    float4 a = x[idx*2], b = x[idx*2+1];
    u16x8 o;
    o[0]=f2h(a.x); o[1]=f2h(a.y); o[2]=f2h(a.z); o[3]=f2h(a.w);
    o[4]=f2h(b.x); o[5]=f2h(b.y); o[6]=f2h(b.z); o[7]=f2h(b.w);
    xh[idx] = o;
    return;
  }
  int pidx = idx - N8;
  const int TOT1 = NL*288*CC;      // Wc: (l, col, k)
  const int TOT2 = 288*CC;         // Whh: (col, k), replicated to all layers
  if(pidx < TOT1){
    int k = pidx % CC;
    int col = (pidx / CC) % 288;
    int l = pidx / (CC*288);
    // Wc[k][col] = sum_k2 weight[l][k][k2] * w_ih[col][k2]
    const float4* wr = (const float4*)(weight + (size_t)(l*CC + k)*CC);
    const float4* ir = (const float4*)(w_ih + (size_t)col*CC);
    float acc = 0.f;
    #pragma unroll 4
    for(int k2=0;k2<CC/4;k2++){
      float4 a = wr[k2], b = ir[k2];
      acc += a.x*b.x + a.y*b.y + a.z*b.z + a.w*b.w;
    }
    int g = col / 96, cg = col % 96;
    int tcol = cg >> 4, n = cg & 15;
    int ks = k >> 5, r = (k & 31) >> 3, j = k & 7;
    int lane = r*16 + n;
    gw[(size_t)l*ELEMS_PER_LAYER + frag_elem(tcol, g, ks, lane, j)] = f2h(acc);
  } else {
    int idx2 = pidx - TOT1;
    if(idx2 < TOT2){
      int k = idx2 % CC;
      int col = idx2 / CC;
      uint16_t h = f2h(w_hh[(size_t)col*CC + k]);   // gh = x @ w_hh^T: B[k][col] = w_hh[col][k]
      int g = col / 96, cg = col % 96;
      int tcol = cg >> 4, n = cg & 15;
      int ks = k >> 5, r = (k & 31) >> 3, j = k & 7;
      int lane = r*16 + n;
      size_t fe = frag_elem(tcol, 3+g, ks, lane, j);
      #pragma unroll
      for(int l=0;l<NL;l++) gw[(size_t)l*ELEMS_PER_LAYER + fe] = h;
    }
  }
}

// Degree-balanced CSR aggregation: ONE WAVE PER NODE. Lane = (c8, e):
// 12 channel-groups x 4 edge-lanes (lanes 48-63 idle). Edge loop strides 4
// (unroll 2 -> 8 gathers in flight); 2-step shfl_down folds the 4 edge
// partials. Wave runtime is proportional to the node's OWN degree — no
// straggler tax from wave-mates (R8's layout paid max-deg over 5.33 nodes).
__global__ void k_aggregate(const u16x8* __restrict__ xh, const int* __restrict__ offsets,
                            const int* __restrict__ counts, const uint16_t* __restrict__ ssrc,
                            u16x8* __restrict__ s16){
  int w = (blockIdx.x*256 + threadIdx.x) >> 6;    // wave id = node
  int lane = threadIdx.x & 63;
  if(w >= NN) return;
  int c8 = lane >> 2;         // 0..15 (12..15 idle)
  int e  = lane & 3;
  bool active = (c8 < 12);
  int o0 = offsets[w];
  int o1 = o0 + counts[w];
  float a[8];
  #pragma unroll
  for(int t=0;t<8;t++) a[t] = 0.f;
  if(active){
    int j = o0 + e;
    for(; j+4 < o1; j += 8){
      int s0 = ssrc[j], s1 = ssrc[j+4];
      u16x8 v0 = xh[(size_t)s0*12 + c8];
      u16x8 v1 = xh[(size_t)s1*12 + c8];
      #pragma unroll
      for(int t=0;t<8;t++) a[t] += h2f(v0[t]) + h2f(v1[t]);
    }
    if(j < o1){
      u16x8 v = xh[(size_t)ssrc[j]*12 + c8];
      #pragma unroll
      for(int t=0;t<8;t++) a[t] += h2f(v[t]);
    }
  }
  // fold e=0..3 partials within each 4-lane group
  #pragma unroll
  for(int t=0;t<8;t++){
    a[t] += __shfl_down(a[t], 1, 64);
    a[t] += __shfl_down(a[t], 2, 64);
  }
  if(active && e == 0){
    u16x8 o;
    #pragma unroll
    for(int t=0;t<8;t++) o[t] = f2h(a[t]);
    s16[(size_t)w*12 + c8] = o;
  }
}

#define MFMA16(A,B,C) __builtin_amdgcn_mfma_f32_16x16x32_f16(A,B,C,0,0,0)

// Fused dual-GEMM + GRU (R8 shape: 1024 threads = 16 waves/CU, 1 mtile/wave,
// single barrier, entire 108 KB layer weight set staged to LDS once).
__global__ __launch_bounds__(1024) void k_gru(
    const uint16_t* __restrict__ s16, const uint16_t* __restrict__ x16,
    const uint16_t* __restrict__ gw_l,
    const float* __restrict__ b_ih, const float* __restrict__ b_hh,
    float* __restrict__ out_f, uint16_t* __restrict__ out_h16)
{
  __shared__ __align__(16) uint16_t lw[ELEMS_PER_LAYER];   // 110592 B

  const int tid = threadIdx.x;
  // stage all 108 KB: 6912 uint4 chunks over 1024 threads
  {
    const uint4* src = (const uint4*)gw_l;
    uint4* dst = (uint4*)lw;
    #pragma unroll
    for(int i=0;i<7;i++){
      int chunk = i*1024 + tid;
      if(chunk < ELEMS_PER_LAYER/8) dst[chunk] = src[chunk];
    }
  }
  __syncthreads();                        // the only barrier

  int wave = tid >> 6;
  int lane = tid & 63;
  int mtile = wave*256 + blockIdx.x;      // cyclic: all 256 blocks/CUs busy
  if(mtile >= NMT) return;                // no more barriers -> early return ok
  int nidx = lane & 15;
  int quad = lane >> 4;

  // A fragments: direct u16x8 loads from fp16 tables (A: m=lane&15, k=quad*8+j)
  f16x8 as[3], ax[3];
  {
    size_t arow = (size_t)(mtile*16 + nidx)*CC;
    #pragma unroll
    for(int ks=0; ks<3; ks++){
      int ko = ks*32 + quad*8;
      as[ks] = *reinterpret_cast<const f16x8*>(s16 + arow + ko);
      ax[ks] = *reinterpret_cast<const f16x8*>(x16 + arow + ko);
    }
  }

  #pragma unroll 1
  for(int tcol=0; tcol<6; tcol++){
    f32x4 air = {0.f,0.f,0.f,0.f}, aiz = {0.f,0.f,0.f,0.f}, ain = {0.f,0.f,0.f,0.f};
    f32x4 ahr = {0.f,0.f,0.f,0.f}, ahz = {0.f,0.f,0.f,0.f}, ahn = {0.f,0.f,0.f,0.f};

    #pragma unroll
    for(int ks=0; ks<3; ks++){
      const uint16_t* base = lw + (((size_t)tcol*6)*3 + ks)*512 + lane*8;
      #define BFRAG(g2) (*reinterpret_cast<const f16x8*>(base + (size_t)(g2)*3*512))
      air = MFMA16(as[ks], BFRAG(0), air);
      aiz = MFMA16(as[ks], BFRAG(1), aiz);
      ain = MFMA16(as[ks], BFRAG(2), ain);
      ahr = MFMA16(ax[ks], BFRAG(3), ahr);
      ahz = MFMA16(ax[ks], BFRAG(4), ahz);
      ahn = MFMA16(ax[ks], BFRAG(5), ahn);
      #undef BFRAG
    }

    int c = tcol*16 + nidx;
    float bir_ = b_ih[c], biz_ = b_ih[CC+c], bin_ = b_ih[2*CC+c];
    float bhr_ = b_hh[c], bhz_ = b_hh[CC+c], bhn_ = b_hh[2*CC+c];

    #pragma unroll
    for(int r=0;r<4;r++){
      int node = mtile*16 + quad*4 + r;   // C/D: row = quad*4 + reg, col = lane&15
      float ir  = air[r] + bir_;
      float iz  = aiz[r] + biz_;
      float in_ = ain[r] + bin_;
      float hr  = ahr[r] + bhr_;
      float hz  = ahz[r] + bhz_;
      float hn  = ahn[r] + bhn_;
      float rg = 1.f/(1.f + __expf(-(ir+hr)));
      float zg = 1.f/(1.f + __expf(-(iz+hz)));
      float nv = in_ + rg*hn;
      float av = fminf(fabsf(nv), 15.f);
      float e2 = __expf(2.f*av);
      float tg = 1.f - 2.f/(e2 + 1.f);
      tg = (nv < 0.f)? -tg : tg;
      size_t oi = (size_t)node*CC + c;
      float hp = h2f(x16[oi]);            // h state lives in the fp16 table
      float h = (1.f - zg)*tg + zg*hp;
      if(out_f)   out_f[oi] = h;          // final layer only (d_out, f32)
      if(out_h16) out_h16[oi] = f2h(h);   // intermediate layers (fp16 ping-pong)
    }
  }
}

extern "C" void kernel_launch(void* const* d_in, const int* in_sizes, int n_in,
                              void* d_out, int out_size, void* d_ws, size_t ws_size,
                              hipStream_t stream){
  const float* x0     = (const float*)d_in[0];
  const int*   ei     = (const int*)d_in[1];
  const float* weight = (const float*)d_in[2];
  const float* w_ih   = (const float*)d_in[3];
  const float* w_hh   = (const float*)d_in[4];
  const float* b_ih   = (const float*)d_in[5];
  const float* b_hh   = (const float*)d_in[6];
  float* out = (float*)d_out;

  const int* srcv = ei;        // edge_index[0]
  const int* dstv = ei + NE;   // edge_index[1]

  char* ws = (char*)d_ws;
  size_t off = 0;
  auto carve = [&](size_t bytes)->char*{
    char* p = ws + off;
    off += (bytes + 255) & ~(size_t)255;
    return p;
  };
  int* counts   = (int*)carve((size_t)NN*4);
  int* offsets  = (int*)carve((size_t)NN*4);
  int* cursor   = (int*)carve((size_t)NN*4);
  int* gcur     = (int*)carve(4);
  uint16_t* ssrc = (uint16_t*)carve((size_t)NE*2);      // uint16 src ids
  uint16_t* s16 = (uint16_t*)carve((size_t)NN*CC*2);    // fp16 aggregate table
  uint16_t* xh16A = (uint16_t*)carve((size_t)NN*CC*2);  // fp16 h table ping
  uint16_t* xh16B = (uint16_t*)carve((size_t)NN*CC*2);  // fp16 h table pong
  uint16_t* gw  = (uint16_t*)carve((size_t)NL*ELEMS_PER_LAYER*2);

  // CSR build (once — edge structure shared by all 3 layers)
  hipMemsetAsync(counts, 0, (size_t)NN*4, stream);
  hipMemsetAsync(gcur, 0, 4, stream);
  k_hist<<<(NE+255)/256, 256, 0, stream>>>(dstv, counts);
  k_assign<<<(NN+255)/256, 256, 0, stream>>>(counts, offsets, cursor, gcur);
  k_fill<<<(NE+255)/256, 256, 0, stream>>>(srcv, dstv, cursor, ssrc);

  // fp16 x table + folded/fragment-packed weights, one dispatch
  k_prep<<<((NN*CC/8 + NL*288*CC + 288*CC)+255)/256, 256, 0, stream>>>(
      (const float4*)x0, (u16x8*)xh16A, weight, w_ih, w_hh, gw);

  uint16_t* xh_cur = xh16A;
  uint16_t* xh_nxt = xh16B;
  for(int l=0; l<NL; l++){
    k_aggregate<<<(NN*64+255)/256, 256, 0, stream>>>(
        (const u16x8*)xh_cur, offsets, counts, ssrc, (u16x8*)s16);
    float* out_f = (l==NL-1) ? out : nullptr;           // f32 only for final output
    uint16_t* oh = (l==NL-1) ? nullptr : xh_nxt;        // fp16 h for next layer
    k_gru<<<256, 1024, 0, stream>>>(s16, xh_cur,
                                    gw + (size_t)l*ELEMS_PER_LAYER,
                                    b_ih, b_hh, out_f, oh);
    xh_cur = xh_nxt; xh_nxt = (xh_cur == xh16A) ? xh16B : xh16A;
  }
}

// Round 12
// 321.868 us; speedup vs baseline: 1.1696x; 1.0678x over previous
//
#include <hip/hip_runtime.h>
#include <hip/hip_bf16.h>
#include <stdint.h>

#define NN 50000
#define NE 800000
#define CC 96
#define NL 3
#define NMT 3125          // M-tiles (16 nodes each)

// fp16 fragment-packed weights: per layer: 6 tcol x 6 sets (0-2 Wc gates, 3-5 Whh gates)
// x 3 ks x 64 lanes x 8 fp16 = 55296 elems = 108 KB
#define ELEMS_PER_LAYER 55296

// fused setup dispatch: hist blocks then prep blocks
#define HIST_BLOCKS 3125                 // 800000/256
#define PREP_ITEMS (NN*CC/8 + NL*288*CC + 288*CC)
#define PREP_BLOCKS ((PREP_ITEMS + 255)/256)

typedef _Float16 f16x8 __attribute__((ext_vector_type(8)));
typedef float f32x4 __attribute__((ext_vector_type(4)));
typedef uint16_t u16x8 __attribute__((ext_vector_type(8)));

__device__ __forceinline__ uint16_t f2h(float f){
  _Float16 h = (_Float16)f;
  return __builtin_bit_cast(uint16_t, h);
}
__device__ __forceinline__ float h2f(uint16_t u){
  return (float)__builtin_bit_cast(_Float16, u);
}

// Scan-free bucket assignment (CSR bucket order is arbitrary): wave-prefix-scan
// + one global-cursor atomic per wave.
__global__ void k_assign(const int* __restrict__ counts, int* __restrict__ offsets,
                         int* __restrict__ cursor, int* __restrict__ gcur){
  int i = blockIdx.x*256 + threadIdx.x;
  int lane = threadIdx.x & 63;
  int v = (i < NN) ? counts[i] : 0;
  int sum = v;
  #pragma unroll
  for(int d=1; d<64; d<<=1){
    int t = __shfl_up(sum, d, 64);
    if(lane >= d) sum += t;
  }
  int total = __shfl(sum, 63, 64);
  int base = 0;
  if(lane == 63) base = atomicAdd(gcur, total);
  base = __shfl(base, 63, 64);
  int off = base + sum - v;
  if(i < NN){ offsets[i] = off; cursor[i] = off; }
}

// CSR fill; ssrc stored as uint16 (node ids < 65536) — halves scatter traffic.
__global__ void k_fill(const int* __restrict__ srcv, const int* __restrict__ dstv,
                       int* __restrict__ cursor, uint16_t* __restrict__ ssrc){
  int e = blockIdx.x*256 + threadIdx.x;
  if(e < NE){
    int d = dstv[e];
    int pos = atomicAdd(&cursor[d], 1);
    ssrc[pos] = (uint16_t)srcv[e];
  }
}

// Fused setup: blocks [0,HIST_BLOCKS) histogram dst degrees (atomic-pipe bound);
// blocks [HIST_BLOCKS, ...) do fp16 x-table cvt + weight fold/pack (VALU/VMEM
// bound). Disjoint resources -> the two phases overlap on the machine.
// fe(tcol,g2,ks,lane,j); g2: 0-2 Wc r/z/n, 3-5 Whh r/z/n.
// B-frag (16x16x32): element (k = ks*32 + (lane>>4)*8 + j, n = lane&15).
__device__ __forceinline__ size_t frag_elem(int tcol, int g2, int ks, int lane, int j){
  return (((size_t)(tcol*6 + g2)*3 + ks)*64 + lane)*8 + j;
}
__global__ void k_setup(const int* __restrict__ dstv, int* __restrict__ counts,
                        const float4* __restrict__ x, u16x8* __restrict__ xh,
                        const float* __restrict__ weight, const float* __restrict__ w_ih,
                        const float* __restrict__ w_hh, uint16_t* __restrict__ gw){
  if(blockIdx.x < HIST_BLOCKS){
    int e = blockIdx.x*256 + threadIdx.x;
    if(e < NE) atomicAdd(&counts[dstv[e]], 1);
    return;
  }
  int idx = (blockIdx.x - HIST_BLOCKS)*256 + threadIdx.x;
  const int N8 = NN*CC/8;          // 600000
  if(idx < N8){
    float4 a = x[idx*2], b = x[idx*2+1];
    u16x8 o;
    o[0]=f2h(a.x); o[1]=f2h(a.y); o[2]=f2h(a.z); o[3]=f2h(a.w);
    o[4]=f2h(b.x); o[5]=f2h(b.y); o[6]=f2h(b.z); o[7]=f2h(b.w);
    xh[idx] = o;
    return;
  }
  int pidx = idx - N8;
  const int TOT1 = NL*288*CC;      // Wc: (l, col, k)
  const int TOT2 = 288*CC;         // Whh: (col, k), replicated to all layers
  if(pidx < TOT1){
    int k = pidx % CC;
    int col = (pidx / CC) % 288;
    int l = pidx / (CC*288);
    // Wc[k][col] = sum_k2 weight[l][k][k2] * w_ih[col][k2]
    const float4* wr = (const float4*)(weight + (size_t)(l*CC + k)*CC);
    const float4* ir = (const float4*)(w_ih + (size_t)col*CC);
    float acc = 0.f;
    #pragma unroll 4
    for(int k2=0;k2<CC/4;k2++){
      float4 a = wr[k2], b = ir[k2];
      acc += a.x*b.x + a.y*b.y + a.z*b.z + a.w*b.w;
    }
    int g = col / 96, cg = col % 96;
    int tcol = cg >> 4, n = cg & 15;
    int ks = k >> 5, r = (k & 31) >> 3, j = k & 7;
    int lane = r*16 + n;
    gw[(size_t)l*ELEMS_PER_LAYER + frag_elem(tcol, g, ks, lane, j)] = f2h(acc);
  } else {
    int idx2 = pidx - TOT1;
    if(idx2 < TOT2){
      int k = idx2 % CC;
      int col = idx2 / CC;
      uint16_t h = f2h(w_hh[(size_t)col*CC + k]);   // gh = x @ w_hh^T: B[k][col] = w_hh[col][k]
      int g = col / 96, cg = col % 96;
      int tcol = cg >> 4, n = cg & 15;
      int ks = k >> 5, r = (k & 31) >> 3, j = k & 7;
      int lane = r*16 + n;
      size_t fe = frag_elem(tcol, 3+g, ks, lane, j);
      #pragma unroll
      for(int l=0;l<NL;l++) gw[(size_t)l*ELEMS_PER_LAYER + fe] = h;
    }
  }
}

// CSR aggregation (R8 shape — max MLP): thread = (node, c8), 16B gathers,
// 8-deep ssrc prefetch (512 outstanding per wave); f32 accumulate, fp16 out.
__global__ void k_aggregate(const u16x8* __restrict__ xh, const int* __restrict__ offsets,
                            const int* __restrict__ counts, const uint16_t* __restrict__ ssrc,
                            u16x8* __restrict__ s16){
  int tid = blockIdx.x*256 + threadIdx.x;
  if(tid >= NN*12) return;
  int n = tid / 12;
  int c8 = tid - n*12;
  int o0 = offsets[n];
  int o1 = o0 + counts[n];
  float a[8];
  #pragma unroll
  for(int t=0;t<8;t++) a[t] = 0.f;
  int j = o0;
  for(; j+8 <= o1; j+=8){
    int s0 = ssrc[j],   s1 = ssrc[j+1], s2 = ssrc[j+2], s3 = ssrc[j+3];
    int s4 = ssrc[j+4], s5 = ssrc[j+5], s6 = ssrc[j+6], s7 = ssrc[j+7];
    u16x8 v0 = xh[(size_t)s0*12 + c8];
    u16x8 v1 = xh[(size_t)s1*12 + c8];
    u16x8 v2 = xh[(size_t)s2*12 + c8];
    u16x8 v3 = xh[(size_t)s3*12 + c8];
    u16x8 v4 = xh[(size_t)s4*12 + c8];
    u16x8 v5 = xh[(size_t)s5*12 + c8];
    u16x8 v6 = xh[(size_t)s6*12 + c8];
    u16x8 v7 = xh[(size_t)s7*12 + c8];
    #pragma unroll
    for(int t=0;t<8;t++)
      a[t] += ((h2f(v0[t])+h2f(v1[t]))+(h2f(v2[t])+h2f(v3[t])))
            + ((h2f(v4[t])+h2f(v5[t]))+(h2f(v6[t])+h2f(v7[t])));
  }
  for(; j < o1; j++){
    u16x8 v = xh[(size_t)ssrc[j]*12 + c8];
    #pragma unroll
    for(int t=0;t<8;t++) a[t] += h2f(v[t]);
  }
  u16x8 o;
  #pragma unroll
  for(int t=0;t<8;t++) o[t] = f2h(a[t]);
  s16[tid] = o;
}

#define MFMA16(A,B,C) __builtin_amdgcn_mfma_f32_16x16x32_f16(A,B,C,0,0,0)

// Fused dual-GEMM + GRU (R8 shape: 1024 threads = 16 waves/CU, 1 mtile/wave,
// single barrier). A-fragment global loads are issued BEFORE the staging loop
// so their latency overlaps the LDS writes (they drain at the barrier anyway).
__global__ __launch_bounds__(1024) void k_gru(
    const uint16_t* __restrict__ s16, const uint16_t* __restrict__ x16,
    const uint16_t* __restrict__ gw_l,
    const float* __restrict__ b_ih, const float* __restrict__ b_hh,
    float* __restrict__ out_f, uint16_t* __restrict__ out_h16)
{
  __shared__ __align__(16) uint16_t lw[ELEMS_PER_LAYER];   // 110592 B

  const int tid = threadIdx.x;
  int wave = tid >> 6;
  int lane = tid & 63;
  int mtile = wave*256 + blockIdx.x;      // cyclic: all 256 blocks/CUs busy
  bool valid = (mtile < NMT);
  int mt = valid ? mtile : 0;
  int nidx = lane & 15;
  int quad = lane >> 4;

  // A fragments first (global, ~600 cyc latency) — overlap with staging below
  f16x8 as[3], ax[3];
  {
    size_t arow = (size_t)(mt*16 + nidx)*CC;
    #pragma unroll
    for(int ks=0; ks<3; ks++){
      int ko = ks*32 + quad*8;
      as[ks] = *reinterpret_cast<const f16x8*>(s16 + arow + ko);
      ax[ks] = *reinterpret_cast<const f16x8*>(x16 + arow + ko);
    }
  }

  // stage all 108 KB: 6912 uint4 chunks over 1024 threads
  {
    const uint4* src = (const uint4*)gw_l;
    uint4* dst = (uint4*)lw;
    #pragma unroll
    for(int i=0;i<7;i++){
      int chunk = i*1024 + tid;
      if(chunk < ELEMS_PER_LAYER/8) dst[chunk] = src[chunk];
    }
  }
  __syncthreads();                        // the only barrier
  if(!valid) return;                      // idle waves exit after barrier

  #pragma unroll 1
  for(int tcol=0; tcol<6; tcol++){
    f32x4 air = {0.f,0.f,0.f,0.f}, aiz = {0.f,0.f,0.f,0.f}, ain = {0.f,0.f,0.f,0.f};
    f32x4 ahr = {0.f,0.f,0.f,0.f}, ahz = {0.f,0.f,0.f,0.f}, ahn = {0.f,0.f,0.f,0.f};

    #pragma unroll
    for(int ks=0; ks<3; ks++){
      const uint16_t* base = lw + (((size_t)tcol*6)*3 + ks)*512 + lane*8;
      #define BFRAG(g2) (*reinterpret_cast<const f16x8*>(base + (size_t)(g2)*3*512))
      air = MFMA16(as[ks], BFRAG(0), air);
      aiz = MFMA16(as[ks], BFRAG(1), aiz);
      ain = MFMA16(as[ks], BFRAG(2), ain);
      ahr = MFMA16(ax[ks], BFRAG(3), ahr);
      ahz = MFMA16(ax[ks], BFRAG(4), ahz);
      ahn = MFMA16(ax[ks], BFRAG(5), ahn);
      #undef BFRAG
    }

    int c = tcol*16 + nidx;
    float bir_ = b_ih[c], biz_ = b_ih[CC+c], bin_ = b_ih[2*CC+c];
    float bhr_ = b_hh[c], bhz_ = b_hh[CC+c], bhn_ = b_hh[2*CC+c];

    #pragma unroll
    for(int r=0;r<4;r++){
      int node = mtile*16 + quad*4 + r;   // C/D: row = quad*4 + reg, col = lane&15
      float ir  = air[r] + bir_;
      float iz  = aiz[r] + biz_;
      float in_ = ain[r] + bin_;
      float hr  = ahr[r] + bhr_;
      float hz  = ahz[r] + bhz_;
      float hn  = ahn[r] + bhn_;
      float rg = 1.f/(1.f + __expf(-(ir+hr)));
      float zg = 1.f/(1.f + __expf(-(iz+hz)));
      float nv = in_ + rg*hn;
      float av = fminf(fabsf(nv), 15.f);
      float e2 = __expf(2.f*av);
      float tg = 1.f - 2.f/(e2 + 1.f);
      tg = (nv < 0.f)? -tg : tg;
      size_t oi = (size_t)node*CC + c;
      float hp = h2f(x16[oi]);            // h state lives in the fp16 table
      float h = (1.f - zg)*tg + zg*hp;
      if(out_f)   out_f[oi] = h;          // final layer only (d_out, f32)
      if(out_h16) out_h16[oi] = f2h(h);   // intermediate layers (fp16 ping-pong)
    }
  }
}

extern "C" void kernel_launch(void* const* d_in, const int* in_sizes, int n_in,
                              void* d_out, int out_size, void* d_ws, size_t ws_size,
                              hipStream_t stream){
  const float* x0     = (const float*)d_in[0];
  const int*   ei     = (const int*)d_in[1];
  const float* weight = (const float*)d_in[2];
  const float* w_ih   = (const float*)d_in[3];
  const float* w_hh   = (const float*)d_in[4];
  const float* b_ih   = (const float*)d_in[5];
  const float* b_hh   = (const float*)d_in[6];
  float* out = (float*)d_out;

  const int* srcv = ei;        // edge_index[0]
  const int* dstv = ei + NE;   // edge_index[1]

  char* ws = (char*)d_ws;
  size_t off = 0;
  auto carve = [&](size_t bytes)->char*{
    char* p = ws + off;
    off += (bytes + 255) & ~(size_t)255;
    return p;
  };
  int* counts   = (int*)carve((size_t)NN*4);
  int* offsets  = (int*)carve((size_t)NN*4);
  int* cursor   = (int*)carve((size_t)NN*4);
  int* gcur     = (int*)carve(4);
  uint16_t* ssrc = (uint16_t*)carve((size_t)NE*2);      // uint16 src ids
  uint16_t* s16 = (uint16_t*)carve((size_t)NN*CC*2);    // fp16 aggregate table
  uint16_t* xh16A = (uint16_t*)carve((size_t)NN*CC*2);  // fp16 h table ping
  uint16_t* xh16B = (uint16_t*)carve((size_t)NN*CC*2);  // fp16 h table pong
  uint16_t* gw  = (uint16_t*)carve((size_t)NL*ELEMS_PER_LAYER*2);

  // CSR build + prep. hist and prep are fused into one dispatch (disjoint
  // block ranges; atomic-bound + VALU-bound work overlaps).
  hipMemsetAsync(counts, 0, (size_t)NN*4, stream);
  hipMemsetAsync(gcur, 0, 4, stream);
  k_setup<<<HIST_BLOCKS + PREP_BLOCKS, 256, 0, stream>>>(
      dstv, counts, (const float4*)x0, (u16x8*)xh16A, weight, w_ih, w_hh, gw);
  k_assign<<<(NN+255)/256, 256, 0, stream>>>(counts, offsets, cursor, gcur);
  k_fill<<<(NE+255)/256, 256, 0, stream>>>(srcv, dstv, cursor, ssrc);

  uint16_t* xh_cur = xh16A;
  uint16_t* xh_nxt = xh16B;
  for(int l=0; l<NL; l++){
    k_aggregate<<<((NN*12)+255)/256, 256, 0, stream>>>(
        (const u16x8*)xh_cur, offsets, counts, ssrc, (u16x8*)s16);
    float* out_f = (l==NL-1) ? out : nullptr;           // f32 only for final output
    uint16_t* oh = (l==NL-1) ? nullptr : xh_nxt;        // fp16 h for next layer
    k_gru<<<256, 1024, 0, stream>>>(s16, xh_cur,
                                    gw + (size_t)l*ELEMS_PER_LAYER,
                                    b_ih, b_hh, out_f, oh);
    xh_cur = xh_nxt; xh_nxt = (xh_cur == xh16A) ? xh16B : xh16A;
  }
}